// Round 9
// baseline (368.527 us; speedup 1.0000x reference)
//
#include <hip/hip_runtime.h>
#include <hip/hip_bf16.h>
#include <float.h>
#include <math.h>

#define HH 16
#define DH 64
#define NS 1024
#define SCALE 0.125f
#define KTOP 32
#define NEGF (-FLT_MAX)

typedef __attribute__((ext_vector_type(8))) short short8;
typedef __attribute__((ext_vector_type(4))) short short4v;
typedef __attribute__((ext_vector_type(4))) float f32x4;
typedef unsigned short ushort_t;

__device__ __forceinline__ ushort_t f2b(float f) {
    __hip_bfloat16 h = __float2bfloat16(f);
    return *reinterpret_cast<ushort_t*>(&h);
}
__device__ __forceinline__ float b2f(ushort_t u) {
    unsigned x = ((unsigned)u) << 16;
    return __uint_as_float(x);
}

// ---------------- K0b: f32 [K=1024][N] -> bf16 transposed [N][1024] ----------------
__global__ __launch_bounds__(256) void k0_tr(const float* __restrict__ src,
        ushort_t* __restrict__ dst, int N) {
    __shared__ float sh[32][33];
    int tx = threadIdx.x & 31, ty = threadIdx.x >> 5;
    int n0 = blockIdx.x * 32, k0 = blockIdx.y * 32;
    #pragma unroll
    for (int e = 0; e < 4; ++e) {
        int r = ty + e*8;
        sh[r][tx] = src[(k0 + r)*N + n0 + tx];
    }
    __syncthreads();
    #pragma unroll
    for (int e = 0; e < 4; ++e) {
        int r = ty + e*8;
        dst[(n0 + r)*1024 + k0 + tx] = f2b(sh[tx][r]);
    }
}

// ---------------- K1: QKV projection, bf16 MFMA 128x128 tile, fp32 x staged+converted inline ----------------
__global__ __launch_bounds__(256) void k1_mfma(const float* __restrict__ xf,
        const ushort_t* __restrict__ Wt, ushort_t* __restrict__ qb,
        ushort_t* __restrict__ kbf, ushort_t* __restrict__ vb) {
    __shared__ ushort_t As[128*40];
    __shared__ ushort_t Bs[128*40];
    int t = threadIdx.x;
    int lane = t & 63, w = t >> 6;
    int wm = w >> 1, wn = w & 1;
    int row_l = lane & 15, grp = lane >> 4;
    int row0 = blockIdx.y * 128, col0 = blockIdx.x * 128;
    f32x4 acc[4][4];
    f32x4 zz = {0.f, 0.f, 0.f, 0.f};
    #pragma unroll
    for (int mi = 0; mi < 4; ++mi)
        #pragma unroll
        for (int ni = 0; ni < 4; ++ni) acc[mi][ni] = zz;
    for (int k0 = 0; k0 < 1024; k0 += 32) {
        #pragma unroll
        for (int e = 0; e < 2; ++e) {
            int slot = t + 256*e;
            int r = slot >> 2, kbk = slot & 3;
            const float* xs = xf + (size_t)(row0 + r)*1024 + k0 + kbk*8;
            float4 xa = *(const float4*)(xs);
            float4 xbv = *(const float4*)(xs + 4);
            short8 vA;
            vA[0]=f2b(xa.x); vA[1]=f2b(xa.y); vA[2]=f2b(xa.z); vA[3]=f2b(xa.w);
            vA[4]=f2b(xbv.x); vA[5]=f2b(xbv.y); vA[6]=f2b(xbv.z); vA[7]=f2b(xbv.w);
            *(short8*)(As + r*40 + kbk*8) = vA;
            short8 vB = *(const short8*)(Wt + (size_t)(col0 + r)*1024 + k0 + kbk*8);
            *(short8*)(Bs + r*40 + kbk*8) = vB;
        }
        __syncthreads();
        short8 a[4], b[4];
        #pragma unroll
        for (int mi = 0; mi < 4; ++mi)
            a[mi] = *(const short8*)(As + (wm*64 + mi*16 + row_l)*40 + grp*8);
        #pragma unroll
        for (int ni = 0; ni < 4; ++ni)
            b[ni] = *(const short8*)(Bs + (wn*64 + ni*16 + row_l)*40 + grp*8);
        #pragma unroll
        for (int mi = 0; mi < 4; ++mi)
            #pragma unroll
            for (int ni = 0; ni < 4; ++ni)
                acc[mi][ni] = __builtin_amdgcn_mfma_f32_16x16x32_bf16(
                    a[mi], b[ni], acc[mi][ni], 0, 0, 0);
        __syncthreads();
    }
    #pragma unroll
    for (int mi = 0; mi < 4; ++mi)
        #pragma unroll
        for (int ni = 0; ni < 4; ++ni)
            #pragma unroll
            for (int rg = 0; rg < 4; ++rg) {
                int grow = row0 + wm*64 + mi*16 + grp*4 + rg;
                int gcol = col0 + wn*64 + ni*16 + row_l;
                float val = acc[mi][ni][rg];
                int b_ = grow >> 10, i = grow & 1023;
                int which = gcol >> 10, cc = gcol & 1023;
                int h = cc >> 6, d = cc & 63;
                int idx = (((b_*HH + h)*NS) + i)*DH + d;
                if (which == 0)      qb[idx]  = f2b(val);
                else if (which == 1) kbf[idx] = f2b(val);
                else                 vb[idx]  = f2b(val);
            }
}

// ---------------- K4: v (b,h,i,d) bf16 -> vT (b,h,d,i) bf16 ----------------
__global__ __launch_bounds__(256) void k4_vt(const ushort_t* __restrict__ vb,
        ushort_t* __restrict__ vT) {
    __shared__ ushort_t sh[32][33];
    int bh = blockIdx.z;
    int d0 = blockIdx.x * 32;
    int i0 = blockIdx.y * 32;
    int tx = threadIdx.x & 31, ty = threadIdx.x >> 5;
    #pragma unroll
    for (int e = 0; e < 4; ++e) {
        int r = ty + e*8;
        sh[r][tx] = vb[((size_t)bh*NS + i0 + r)*DH + d0 + tx];
    }
    __syncthreads();
    #pragma unroll
    for (int e = 0; e < 4; ++e) {
        int r = ty + e*8;
        vT[((size_t)bh*DH + d0 + r)*NS + i0 + tx] = sh[tx][r];
    }
}

// ---------------- K2: scores (MFMA) + pre-softmax talking-heads mix ----------------
__global__ __launch_bounds__(256) void k2_scores(const ushort_t* __restrict__ qb,
        const ushort_t* __restrict__ kbf, const float* __restrict__ rel,
        const float* __restrict__ pre, float* __restrict__ dots) {
    int t = threadIdx.x & 63;
    int w = threadIdx.x >> 6;
    int wid = blockIdx.x * 4 + w;
    int b_ = (wid >= 2080) ? 1 : 0;
    int r = wid - 2080*b_;
    int i16 = (int)((sqrtf(8.0f*(float)r + 1.0f) - 1.0f) * 0.5f);
    while ((i16+1)*(i16+2)/2 <= r) ++i16;
    while (i16*(i16+1)/2 > r) --i16;
    int j16 = r - i16*(i16+1)/2;
    int row_l = t & 15, grp = t >> 4;
    int qrow = i16*16 + row_l;
    int krow = j16*16 + row_l;
    int dbase = grp*8;
    float acc[16][4];
    #pragma unroll
    for (int kp = 0; kp < 16; ++kp)
        #pragma unroll
        for (int rg = 0; rg < 4; ++rg) acc[kp][rg] = 0.f;
    #pragma unroll 4
    for (int h = 0; h < HH; ++h) {
        const ushort_t* qh = qb + (((b_*HH + h)*NS) + qrow)*DH;
        const ushort_t* kh = kbf + (((b_*HH + h)*NS) + krow)*DH;
        short8 a0 = *(const short8*)(qh + dbase);
        short8 a1 = *(const short8*)(qh + 32 + dbase);
        short8 b0 = *(const short8*)(kh + dbase);
        short8 b1 = *(const short8*)(kh + 32 + dbase);
        f32x4 s = {0.f, 0.f, 0.f, 0.f};
        s = __builtin_amdgcn_mfma_f32_16x16x32_bf16(a0, b0, s, 0, 0, 0);
        s = __builtin_amdgcn_mfma_f32_16x16x32_bf16(a1, b1, s, 0, 0, 0);
        float pr[16];
        #pragma unroll
        for (int kp = 0; kp < 16; ++kp) pr[kp] = pre[h*16 + kp];
        #pragma unroll
        for (int rg = 0; rg < 4; ++rg) {
            int gi = i16*16 + grp*4 + rg;
            int gj = j16*16 + row_l;
            float tv = s[rg]*SCALE + rel[(h*NS + gi)*NS + gj];
            #pragma unroll
            for (int kp = 0; kp < 16; ++kp) acc[kp][rg] += tv * pr[kp];
        }
    }
    int gj = j16*16 + row_l;
    #pragma unroll
    for (int kp = 0; kp < 16; ++kp)
        #pragma unroll
        for (int rg = 0; rg < 4; ++rg) {
            int gi = i16*16 + grp*4 + rg;
            dots[(((b_*HH + kp)*NS) + gi)*NS + gj] = acc[kp][rg];
        }
}

// ---------------- K3 helper: causal mask + top-k (24-step ballot search) + softmax -> bf16 LDS ----------------
template<int NC>
__device__ __forceinline__ void topk_row(const float* __restrict__ rowp,
        ushort_t* __restrict__ scRow, int i, int l) {
    float v[NC*4];
    unsigned u[NC*4];
    #pragma unroll
    for (int c = 0; c < NC; ++c) {
        float4 t4 = *(const float4*)(rowp + c*256 + l*4);
        v[c*4+0] = t4.x; v[c*4+1] = t4.y; v[c*4+2] = t4.z; v[c*4+3] = t4.w;
    }
    #pragma unroll
    for (int c = 0; c < NC; ++c) {
        int j0 = c*256 + l*4;
        #pragma unroll
        for (int e = 0; e < 4; ++e)
            if (j0 + e > i) v[c*4+e] = NEGF;
    }
    float m = NEGF;
    #pragma unroll
    for (int e = 0; e < NC*4; ++e) m = fmaxf(m, v[e]);
    #pragma unroll
    for (int o = 32; o; o >>= 1) m = fmaxf(m, __shfl_xor(m, o));
    #pragma unroll
    for (int e = 0; e < NC*4; ++e) {
        unsigned x = __float_as_uint(v[e]);
        u[e] = x ^ ((unsigned)(((int)x) >> 31) | 0x80000000u);
    }
    // 24-step binary search over bits 31..8: thr exact to 2^-15 relative —
    // selection flips only for pairs closer than that (tie-class, negligible)
    unsigned thr = 0u;
    for (int bit = 31; bit >= 8; --bit) {
        unsigned cand = thr | (1u << bit);
        int cnt = 0;
        #pragma unroll
        for (int e = 0; e < NC*4; ++e)
            cnt += __popcll(__ballot(u[e] >= cand));
        if (cnt >= KTOP) thr = cand;
    }
    float ssum = 0.f;
    #pragma unroll
    for (int e = 0; e < NC*4; ++e) {
        float ev = (u[e] >= thr) ? __expf(v[e] - m) : 0.f;
        v[e] = ev; ssum += ev;
    }
    #pragma unroll
    for (int o = 32; o; o >>= 1) ssum += __shfl_xor(ssum, o);
    float inv = 1.0f / ssum;
    #pragma unroll
    for (int c = 0; c < NC; ++c) {
        short4v o4;
        o4[0] = (short)f2b(v[c*4+0] * inv);
        o4[1] = (short)f2b(v[c*4+1] * inv);
        o4[2] = (short)f2b(v[c*4+2] * inv);
        o4[3] = (short)f2b(v[c*4+3] * inv);
        *(short4v*)(scRow + c*256 + l*4) = o4;
    }
    short4v z4 = {0, 0, 0, 0};
    #pragma unroll
    for (int c = NC; c < 4; ++c)
        *(short4v*)(scRow + c*256 + l*4) = z4;
}

// ---------------- K3: topk+softmax per head-wave; post-mix written bf16 packed in place ----------------
// bf16 P row (b,kp,i) occupies the FIRST 2048 bytes of the fp32 dots row (b,kp,i).
__global__ __launch_bounds__(1024, 4) void k3_topk(float* __restrict__ dots,
        const float* __restrict__ post) {
    __shared__ ushort_t sc[HH][NS];   // 32 KB bf16 probs -> 4 blocks/CU
    __shared__ float postS[HH][HH];
    int t = threadIdx.x;
    int bi = blockIdx.x;
    int b_ = bi >> 10, i = bi & 1023;
    if (t < 256) postS[t >> 4][t & 15] = post[t];
    int w = t >> 6;
    int l = t & 63;
    const float* rowp = dots + ((size_t)((b_*HH + w)*NS + i))*NS;
    int nc = (i >> 8) + 1;
    if (nc == 1)      topk_row<1>(rowp, sc[w], i, l);
    else if (nc == 2) topk_row<2>(rowp, sc[w], i, l);
    else if (nc == 3) topk_row<3>(rowp, sc[w], i, l);
    else              topk_row<4>(rowp, sc[w], i, l);
    __syncthreads();
    ushort_t* pb = (ushort_t*)dots;
    float a16[HH];
    #pragma unroll
    for (int h = 0; h < HH; ++h) a16[h] = b2f(sc[h][t]);
    #pragma unroll
    for (int kp = 0; kp < HH; ++kp) {
        float o = 0.f;
        #pragma unroll
        for (int h = 0; h < HH; ++h) o += a16[h] * postS[h][kp];
        pb[(((size_t)(b_*HH + kp)*NS + i)*NS << 1) + t] = f2b(o);
    }
}

// ---------------- K5: PV via MFMA, A = packed bf16 P (global), B = vT (global) ----------------
__global__ __launch_bounds__(256) void k5_pv(const ushort_t* __restrict__ pb,
        const ushort_t* __restrict__ vT, ushort_t* __restrict__ ao) {
    int t = threadIdx.x;
    int lane = t & 63, w = t >> 6;
    int bh = blockIdx.y;
    int i0 = blockIdx.x * 64;
    int row_l = lane & 15, grp = lane >> 4;
    int irow = i0 + w*16 + row_l;
    const ushort_t* pA = pb + (((size_t)bh*NS + irow)*NS << 1);
    const ushort_t* vB = vT + ((size_t)bh*DH + row_l)*NS;
    f32x4 acc[4];
    f32x4 zz = {0.f, 0.f, 0.f, 0.f};
    #pragma unroll
    for (int ni = 0; ni < 4; ++ni) acc[ni] = zz;
    int nsteps = (i0 + 64) >> 5;
    for (int s = 0; s < nsteps; ++s) {
        int j0 = s*32 + grp*8;
        short8 a = *(const short8*)(pA + j0);
        #pragma unroll
        for (int ni = 0; ni < 4; ++ni) {
            short8 b = *(const short8*)(vB + ni*16*NS + j0);
            acc[ni] = __builtin_amdgcn_mfma_f32_16x16x32_bf16(a, b, acc[ni], 0, 0, 0);
        }
    }
    #pragma unroll
    for (int ni = 0; ni < 4; ++ni)
        #pragma unroll
        for (int rg = 0; rg < 4; ++rg)
            ao[((size_t)bh*NS + i0 + w*16 + grp*4 + rg)*DH + ni*16 + row_l] = f2b(acc[ni][rg]);
}

// ---------------- K6: output projection, bf16 MFMA ----------------
__global__ __launch_bounds__(256) void k6_mfma(const ushort_t* __restrict__ aob,
        const ushort_t* __restrict__ Wot, const float* __restrict__ bout,
        float* __restrict__ y) {
    __shared__ ushort_t As[128*40];
    __shared__ ushort_t Bs[128*40];
    int t = threadIdx.x;
    int lane = t & 63, w = t >> 6;
    int wm = w >> 1, wn = w & 1;
    int row_l = lane & 15, grp = lane >> 4;
    int row0 = blockIdx.y * 128, col0 = blockIdx.x * 128;
    f32x4 acc[4][4];
    f32x4 zz = {0.f, 0.f, 0.f, 0.f};
    #pragma unroll
    for (int mi = 0; mi < 4; ++mi)
        #pragma unroll
        for (int ni = 0; ni < 4; ++ni) acc[mi][ni] = zz;
    for (int k0 = 0; k0 < 1024; k0 += 32) {
        #pragma unroll
        for (int e = 0; e < 2; ++e) {
            int slot = t + 256*e;
            int r = slot >> 2, kbk = slot & 3;
            int grow = row0 + r;
            int b_ = grow >> 10, i = grow & 1023;
            int kk0 = k0 + kbk*8;
            int h = kk0 >> 6, d = kk0 & 63;
            short8 vA = *(const short8*)(aob + (((b_*HH + h)*NS) + i)*DH + d);
            *(short8*)(As + r*40 + kbk*8) = vA;
            short8 vB = *(const short8*)(Wot + (size_t)(col0 + r)*1024 + k0 + kbk*8);
            *(short8*)(Bs + r*40 + kbk*8) = vB;
        }
        __syncthreads();
        short8 a[4], b[4];
        #pragma unroll
        for (int mi = 0; mi < 4; ++mi)
            a[mi] = *(const short8*)(As + (wm*64 + mi*16 + row_l)*40 + grp*8);
        #pragma unroll
        for (int ni = 0; ni < 4; ++ni)
            b[ni] = *(const short8*)(Bs + (wn*64 + ni*16 + row_l)*40 + grp*8);
        #pragma unroll
        for (int mi = 0; mi < 4; ++mi)
            #pragma unroll
            for (int ni = 0; ni < 4; ++ni)
                acc[mi][ni] = __builtin_amdgcn_mfma_f32_16x16x32_bf16(
                    a[mi], b[ni], acc[mi][ni], 0, 0, 0);
        __syncthreads();
    }
    #pragma unroll
    for (int mi = 0; mi < 4; ++mi)
        #pragma unroll
        for (int ni = 0; ni < 4; ++ni)
            #pragma unroll
            for (int rg = 0; rg < 4; ++rg) {
                int grow = row0 + wm*64 + mi*16 + grp*4 + rg;
                int gcol = col0 + wn*64 + ni*16 + row_l;
                y[grow*1024 + gcol] = acc[mi][ni][rg] + bout[gcol];
            }
}

extern "C" void kernel_launch(void* const* d_in, const int* in_sizes, int n_in,
                              void* d_out, int out_size, void* d_ws, size_t ws_size,
                              hipStream_t stream) {
    const float* x    = (const float*)d_in[0];
    const float* rel  = (const float*)d_in[1];
    const float* Wq   = (const float*)d_in[2];
    const float* Wkv  = (const float*)d_in[3];
    const float* pre  = (const float*)d_in[4];
    const float* post = (const float*)d_in[5];
    const float* Wout = (const float*)d_in[6];
    const float* bout = (const float*)d_in[7];
    float* out = (float*)d_out;

    float* ws = (float*)d_ws;
    // float-unit offsets (total exactly 160 MiB)
    float*    dots = ws;                               // 33,554,432 fu (bf16 P packed in place)
    ushort_t* vb   = (ushort_t*)(ws + 33554432);       // 2,097,152 bf16
    ushort_t* vT   = (ushort_t*)(ws + 34603008);       // 2,097,152 bf16
    ushort_t* qb   = (ushort_t*)(ws + 35651584);       // 2,097,152 bf16
    ushort_t* kbuf = (ushort_t*)(ws + 36700160);       // 2,097,152 bf16
    ushort_t* Wt   = (ushort_t*)(ws + 38797312);       // 3,145,728 bf16
    ushort_t* Wot  = (ushort_t*)(ws + 40370176);       // 1,048,576 bf16
    ushort_t* aob  = (ushort_t*)(ws + 40894464);       // 2,097,152 bf16

    k0_tr<<<dim3(32, 32), 256, 0, stream>>>(Wq, Wt, 1024);
    k0_tr<<<dim3(64, 32), 256, 0, stream>>>(Wkv, Wt + 1024*1024, 2048);
    k0_tr<<<dim3(32, 32), 256, 0, stream>>>(Wout, Wot, 1024);
    k1_mfma<<<dim3(24, 16), 256, 0, stream>>>(x, Wt, qb, kbuf, vb);
    k4_vt<<<dim3(2, 32, 32), 256, 0, stream>>>(vb, vT);
    k2_scores<<<dim3(1040), 256, 0, stream>>>(qb, kbuf, rel, pre, dots);
    k3_topk<<<dim3(2048), 1024, 0, stream>>>(dots, post);
    k5_pv<<<dim3(16, 32), 256, 0, stream>>>((const ushort_t*)dots, vT, aob);
    k6_mfma<<<dim3(8, 16), 256, 0, stream>>>(aob, Wot, bout, out);
}

// Round 12
// 332.143 us; speedup vs baseline: 1.1095x; 1.1095x over previous
//
#include <hip/hip_runtime.h>
#include <hip/hip_bf16.h>
#include <float.h>
#include <math.h>

#define HH 16
#define DH 64
#define NS 1024
#define SCALE 0.125f
#define KTOP 32
#define NEGF (-FLT_MAX)

typedef __attribute__((ext_vector_type(8))) short short8;
typedef __attribute__((ext_vector_type(4))) float f32x4;
typedef unsigned short ushort_t;

__device__ __forceinline__ ushort_t f2b(float f) {
    __hip_bfloat16 h = __float2bfloat16(f);
    return *reinterpret_cast<ushort_t*>(&h);
}

// ---------------- K0a: f32 -> bf16 convert (x) ----------------
__global__ __launch_bounds__(256) void k0_cvt(const float* __restrict__ src,
        ushort_t* __restrict__ dst, int n8) {
    int i = blockIdx.x * 256 + threadIdx.x;
    if (i >= n8) return;
    const float4* s4 = (const float4*)src;
    float4 a = s4[i*2], b = s4[i*2+1];
    short8 o;
    o[0]=f2b(a.x); o[1]=f2b(a.y); o[2]=f2b(a.z); o[3]=f2b(a.w);
    o[4]=f2b(b.x); o[5]=f2b(b.y); o[6]=f2b(b.z); o[7]=f2b(b.w);
    *(short8*)(dst + i*8) = o;
}

// ---------------- K0b: f32 [K=1024][N] -> bf16 transposed [N][1024] ----------------
__global__ __launch_bounds__(256) void k0_tr(const float* __restrict__ src,
        ushort_t* __restrict__ dst, int N) {
    __shared__ float sh[32][33];
    int tx = threadIdx.x & 31, ty = threadIdx.x >> 5;
    int n0 = blockIdx.x * 32, k0 = blockIdx.y * 32;
    #pragma unroll
    for (int e = 0; e < 4; ++e) {
        int r = ty + e*8;
        sh[r][tx] = src[(k0 + r)*N + n0 + tx];
    }
    __syncthreads();
    #pragma unroll
    for (int e = 0; e < 4; ++e) {
        int r = ty + e*8;
        dst[(n0 + r)*1024 + k0 + tx] = f2b(sh[tx][r]);
    }
}

// ---------------- K1: QKV projection, bf16 MFMA 128x128 tile ----------------
// out: q bf16, k bf16, v bf16 (all (b,h,i,d))
__global__ __launch_bounds__(256) void k1_mfma(const ushort_t* __restrict__ xb,
        const ushort_t* __restrict__ Wt, ushort_t* __restrict__ qb,
        ushort_t* __restrict__ kbf, ushort_t* __restrict__ vb) {
    __shared__ ushort_t As[128*40];
    __shared__ ushort_t Bs[128*40];
    int t = threadIdx.x;
    int lane = t & 63, w = t >> 6;
    int wm = w >> 1, wn = w & 1;
    int row_l = lane & 15, grp = lane >> 4;
    int row0 = blockIdx.y * 128, col0 = blockIdx.x * 128;
    f32x4 acc[4][4];
    f32x4 zz = {0.f, 0.f, 0.f, 0.f};
    #pragma unroll
    for (int mi = 0; mi < 4; ++mi)
        #pragma unroll
        for (int ni = 0; ni < 4; ++ni) acc[mi][ni] = zz;
    for (int k0 = 0; k0 < 1024; k0 += 32) {
        #pragma unroll
        for (int e = 0; e < 2; ++e) {
            int slot = t + 256*e;
            int r = slot >> 2, kbk = slot & 3;
            short8 vA = *(const short8*)(xb + (size_t)(row0 + r)*1024 + k0 + kbk*8);
            *(short8*)(As + r*40 + kbk*8) = vA;
            short8 vB = *(const short8*)(Wt + (size_t)(col0 + r)*1024 + k0 + kbk*8);
            *(short8*)(Bs + r*40 + kbk*8) = vB;
        }
        __syncthreads();
        short8 a[4], b[4];
        #pragma unroll
        for (int mi = 0; mi < 4; ++mi)
            a[mi] = *(const short8*)(As + (wm*64 + mi*16 + row_l)*40 + grp*8);
        #pragma unroll
        for (int ni = 0; ni < 4; ++ni)
            b[ni] = *(const short8*)(Bs + (wn*64 + ni*16 + row_l)*40 + grp*8);
        #pragma unroll
        for (int mi = 0; mi < 4; ++mi)
            #pragma unroll
            for (int ni = 0; ni < 4; ++ni)
                acc[mi][ni] = __builtin_amdgcn_mfma_f32_16x16x32_bf16(
                    a[mi], b[ni], acc[mi][ni], 0, 0, 0);
        __syncthreads();
    }
    #pragma unroll
    for (int mi = 0; mi < 4; ++mi)
        #pragma unroll
        for (int ni = 0; ni < 4; ++ni)
            #pragma unroll
            for (int rg = 0; rg < 4; ++rg) {
                int grow = row0 + wm*64 + mi*16 + grp*4 + rg;
                int gcol = col0 + wn*64 + ni*16 + row_l;
                float val = acc[mi][ni][rg];
                int b_ = grow >> 10, i = grow & 1023;
                int which = gcol >> 10, cc = gcol & 1023;
                int h = cc >> 6, d = cc & 63;
                int idx = (((b_*HH + h)*NS) + i)*DH + d;
                if (which == 0)      qb[idx]  = f2b(val);
                else if (which == 1) kbf[idx] = f2b(val);
                else                 vb[idx]  = f2b(val);
            }
}

// ---------------- K4: v (b,h,i,d) bf16 -> vT (b,h,d,i) bf16 ----------------
__global__ __launch_bounds__(256) void k4_vt(const ushort_t* __restrict__ vb,
        ushort_t* __restrict__ vT) {
    __shared__ ushort_t sh[32][33];
    int bh = blockIdx.z;
    int d0 = blockIdx.x * 32;
    int i0 = blockIdx.y * 32;
    int tx = threadIdx.x & 31, ty = threadIdx.x >> 5;
    #pragma unroll
    for (int e = 0; e < 4; ++e) {
        int r = ty + e*8;
        sh[r][tx] = vb[((size_t)bh*NS + i0 + r)*DH + d0 + tx];
    }
    __syncthreads();
    #pragma unroll
    for (int e = 0; e < 4; ++e) {
        int r = ty + e*8;
        vT[((size_t)bh*DH + d0 + r)*NS + i0 + tx] = sh[tx][r];
    }
}

// ---------------- K2: scores (MFMA) + pre-softmax talking-heads mix ----------------
__global__ __launch_bounds__(256) void k2_scores(const ushort_t* __restrict__ qb,
        const ushort_t* __restrict__ kbf, const float* __restrict__ rel,
        const float* __restrict__ pre, float* __restrict__ dots) {
    int t = threadIdx.x & 63;
    int w = threadIdx.x >> 6;
    int wid = blockIdx.x * 4 + w;
    int b_ = (wid >= 2080) ? 1 : 0;
    int r = wid - 2080*b_;
    int i16 = (int)((sqrtf(8.0f*(float)r + 1.0f) - 1.0f) * 0.5f);
    while ((i16+1)*(i16+2)/2 <= r) ++i16;
    while (i16*(i16+1)/2 > r) --i16;
    int j16 = r - i16*(i16+1)/2;
    int row_l = t & 15, grp = t >> 4;
    int qrow = i16*16 + row_l;
    int krow = j16*16 + row_l;
    int dbase = grp*8;
    float acc[16][4];
    #pragma unroll
    for (int kp = 0; kp < 16; ++kp)
        #pragma unroll
        for (int rg = 0; rg < 4; ++rg) acc[kp][rg] = 0.f;
    #pragma unroll 4
    for (int h = 0; h < HH; ++h) {
        const ushort_t* qh = qb + (((b_*HH + h)*NS) + qrow)*DH;
        const ushort_t* kh = kbf + (((b_*HH + h)*NS) + krow)*DH;
        short8 a0 = *(const short8*)(qh + dbase);
        short8 a1 = *(const short8*)(qh + 32 + dbase);
        short8 b0 = *(const short8*)(kh + dbase);
        short8 b1 = *(const short8*)(kh + 32 + dbase);
        f32x4 s = {0.f, 0.f, 0.f, 0.f};
        s = __builtin_amdgcn_mfma_f32_16x16x32_bf16(a0, b0, s, 0, 0, 0);
        s = __builtin_amdgcn_mfma_f32_16x16x32_bf16(a1, b1, s, 0, 0, 0);
        float pr[16];
        #pragma unroll
        for (int kp = 0; kp < 16; ++kp) pr[kp] = pre[h*16 + kp];
        #pragma unroll
        for (int rg = 0; rg < 4; ++rg) {
            int gi = i16*16 + grp*4 + rg;
            int gj = j16*16 + row_l;
            float tv = s[rg]*SCALE + rel[(h*NS + gi)*NS + gj];
            #pragma unroll
            for (int kp = 0; kp < 16; ++kp) acc[kp][rg] += tv * pr[kp];
        }
    }
    int gj = j16*16 + row_l;
    #pragma unroll
    for (int kp = 0; kp < 16; ++kp)
        #pragma unroll
        for (int rg = 0; rg < 4; ++rg) {
            int gi = i16*16 + grp*4 + rg;
            dots[(((b_*HH + kp)*NS) + gi)*NS + gj] = acc[kp][rg];
        }
}

// ---------------- K3 helper: causal mask + exact top-k via 24-step ballot binary search + softmax ----------------
template<int NC>
__device__ __forceinline__ void topk_row(const float* __restrict__ rowp,
        float* __restrict__ scRow, int i, int l) {
    float v[NC*4];
    unsigned u[NC*4];
    #pragma unroll
    for (int c = 0; c < NC; ++c) {
        float4 t4 = *(const float4*)(rowp + c*256 + l*4);
        v[c*4+0] = t4.x; v[c*4+1] = t4.y; v[c*4+2] = t4.z; v[c*4+3] = t4.w;
    }
    #pragma unroll
    for (int c = 0; c < NC; ++c) {
        int j0 = c*256 + l*4;
        #pragma unroll
        for (int e = 0; e < 4; ++e)
            if (j0 + e > i) v[c*4+e] = NEGF;
    }
    float m = NEGF;
    #pragma unroll
    for (int e = 0; e < NC*4; ++e) m = fmaxf(m, v[e]);
    #pragma unroll
    for (int o = 32; o; o >>= 1) m = fmaxf(m, __shfl_xor(m, o));
    // ordered-uint transform: monotone map fp32 -> u32
    #pragma unroll
    for (int e = 0; e < NC*4; ++e) {
        unsigned x = __float_as_uint(v[e]);
        u[e] = x ^ ((unsigned)(((int)x) >> 31) | 0x80000000u);
    }
    // 24-step binary search over bits 31..8: thr = max{t : count(u>=t) >= KTOP},
    // exact to 2^-15 relative — flips only in the tie-class (negligible)
    unsigned thr = 0u;
    for (int bit = 31; bit >= 8; --bit) {
        unsigned cand = thr | (1u << bit);
        int cnt = 0;
        #pragma unroll
        for (int e = 0; e < NC*4; ++e)
            cnt += __popcll(__ballot(u[e] >= cand));
        if (cnt >= KTOP) thr = cand;
    }
    float ssum = 0.f;
    #pragma unroll
    for (int e = 0; e < NC*4; ++e) {
        float ev = (u[e] >= thr) ? __expf(v[e] - m) : 0.f;
        v[e] = ev; ssum += ev;
    }
    #pragma unroll
    for (int o = 32; o; o >>= 1) ssum += __shfl_xor(ssum, o);
    float inv = 1.0f / ssum;
    #pragma unroll
    for (int c = 0; c < NC; ++c) {
        float4 o4;
        o4.x = v[c*4+0] * inv; o4.y = v[c*4+1] * inv;
        o4.z = v[c*4+2] * inv; o4.w = v[c*4+3] * inv;
        *(float4*)(scRow + c*256 + l*4) = o4;
    }
    float4 z4 = {0.f, 0.f, 0.f, 0.f};
    #pragma unroll
    for (int c = NC; c < 4; ++c)
        *(float4*)(scRow + c*256 + l*4) = z4;
}

// ---------------- K3: topk+softmax per head-wave; post-mix written bf16 packed in place ----------------
// bf16 P row (b,kp,i) occupies the FIRST 2048 bytes of the fp32 dots row (b,kp,i).
__global__ __launch_bounds__(1024, 4) void k3_topk(float* __restrict__ dots,
        const float* __restrict__ post) {
    __shared__ float sc[HH][NS];
    __shared__ float postS[HH][HH];
    int t = threadIdx.x;
    int bi = blockIdx.x;
    int b_ = bi >> 10, i = bi & 1023;
    if (t < 256) postS[t >> 4][t & 15] = post[t];
    int w = t >> 6;
    int l = t & 63;
    const float* rowp = dots + ((size_t)((b_*HH + w)*NS + i))*NS;
    int nc = (i >> 8) + 1;
    if (nc == 1)      topk_row<1>(rowp, sc[w], i, l);
    else if (nc == 2) topk_row<2>(rowp, sc[w], i, l);
    else if (nc == 3) topk_row<3>(rowp, sc[w], i, l);
    else              topk_row<4>(rowp, sc[w], i, l);
    __syncthreads();
    ushort_t* pb = (ushort_t*)dots;
    float a16[HH];
    #pragma unroll
    for (int h = 0; h < HH; ++h) a16[h] = sc[h][t];
    #pragma unroll
    for (int kp = 0; kp < HH; ++kp) {
        float o = 0.f;
        #pragma unroll
        for (int h = 0; h < HH; ++h) o += a16[h] * postS[h][kp];
        pb[(((size_t)(b_*HH + kp)*NS + i)*NS << 1) + t] = f2b(o);
    }
}

// ---------------- K5: PV via MFMA, A = packed bf16 P (global), B = vT (global) ----------------
__global__ __launch_bounds__(256) void k5_pv(const ushort_t* __restrict__ pb,
        const ushort_t* __restrict__ vT, ushort_t* __restrict__ ao) {
    int t = threadIdx.x;
    int lane = t & 63, w = t >> 6;
    int bh = blockIdx.y;
    int i0 = blockIdx.x * 64;
    int row_l = lane & 15, grp = lane >> 4;
    int irow = i0 + w*16 + row_l;
    const ushort_t* pA = pb + (((size_t)bh*NS + irow)*NS << 1);
    const ushort_t* vB = vT + ((size_t)bh*DH + row_l)*NS;
    f32x4 acc[4];
    f32x4 zz = {0.f, 0.f, 0.f, 0.f};
    #pragma unroll
    for (int ni = 0; ni < 4; ++ni) acc[ni] = zz;
    int nsteps = (i0 + 64) >> 5;
    for (int s = 0; s < nsteps; ++s) {
        int j0 = s*32 + grp*8;
        short8 a = *(const short8*)(pA + j0);
        #pragma unroll
        for (int ni = 0; ni < 4; ++ni) {
            short8 b = *(const short8*)(vB + ni*16*NS + j0);
            acc[ni] = __builtin_amdgcn_mfma_f32_16x16x32_bf16(a, b, acc[ni], 0, 0, 0);
        }
    }
    #pragma unroll
    for (int ni = 0; ni < 4; ++ni)
        #pragma unroll
        for (int rg = 0; rg < 4; ++rg)
            ao[((size_t)bh*NS + i0 + w*16 + grp*4 + rg)*DH + ni*16 + row_l] = f2b(acc[ni][rg]);
}

// ---------------- K6: output projection, bf16 MFMA ----------------
__global__ __launch_bounds__(256) void k6_mfma(const ushort_t* __restrict__ aob,
        const ushort_t* __restrict__ Wot, const float* __restrict__ bout,
        float* __restrict__ y) {
    __shared__ ushort_t As[128*40];
    __shared__ ushort_t Bs[128*40];
    int t = threadIdx.x;
    int lane = t & 63, w = t >> 6;
    int wm = w >> 1, wn = w & 1;
    int row_l = lane & 15, grp = lane >> 4;
    int row0 = blockIdx.y * 128, col0 = blockIdx.x * 128;
    f32x4 acc[4][4];
    f32x4 zz = {0.f, 0.f, 0.f, 0.f};
    #pragma unroll
    for (int mi = 0; mi < 4; ++mi)
        #pragma unroll
        for (int ni = 0; ni < 4; ++ni) acc[mi][ni] = zz;
    for (int k0 = 0; k0 < 1024; k0 += 32) {
        #pragma unroll
        for (int e = 0; e < 2; ++e) {
            int slot = t + 256*e;
            int r = slot >> 2, kbk = slot & 3;
            int grow = row0 + r;
            int b_ = grow >> 10, i = grow & 1023;
            int kk0 = k0 + kbk*8;
            int h = kk0 >> 6, d = kk0 & 63;
            short8 vA = *(const short8*)(aob + (((b_*HH + h)*NS) + i)*DH + d);
            *(short8*)(As + r*40 + kbk*8) = vA;
            short8 vB = *(const short8*)(Wot + (size_t)(col0 + r)*1024 + k0 + kbk*8);
            *(short8*)(Bs + r*40 + kbk*8) = vB;
        }
        __syncthreads();
        short8 a[4], b[4];
        #pragma unroll
        for (int mi = 0; mi < 4; ++mi)
            a[mi] = *(const short8*)(As + (wm*64 + mi*16 + row_l)*40 + grp*8);
        #pragma unroll
        for (int ni = 0; ni < 4; ++ni)
            b[ni] = *(const short8*)(Bs + (wn*64 + ni*16 + row_l)*40 + grp*8);
        #pragma unroll
        for (int mi = 0; mi < 4; ++mi)
            #pragma unroll
            for (int ni = 0; ni < 4; ++ni)
                acc[mi][ni] = __builtin_amdgcn_mfma_f32_16x16x32_bf16(
                    a[mi], b[ni], acc[mi][ni], 0, 0, 0);
        __syncthreads();
    }
    #pragma unroll
    for (int mi = 0; mi < 4; ++mi)
        #pragma unroll
        for (int ni = 0; ni < 4; ++ni)
            #pragma unroll
            for (int rg = 0; rg < 4; ++rg) {
                int grow = row0 + wm*64 + mi*16 + grp*4 + rg;
                int gcol = col0 + wn*64 + ni*16 + row_l;
                y[grow*1024 + gcol] = acc[mi][ni][rg] + bout[gcol];
            }
}

extern "C" void kernel_launch(void* const* d_in, const int* in_sizes, int n_in,
                              void* d_out, int out_size, void* d_ws, size_t ws_size,
                              hipStream_t stream) {
    const float* x    = (const float*)d_in[0];
    const float* rel  = (const float*)d_in[1];
    const float* Wq   = (const float*)d_in[2];
    const float* Wkv  = (const float*)d_in[3];
    const float* pre  = (const float*)d_in[4];
    const float* post = (const float*)d_in[5];
    const float* Wout = (const float*)d_in[6];
    const float* bout = (const float*)d_in[7];
    float* out = (float*)d_out;

    float* ws = (float*)d_ws;
    // float-unit offsets (total exactly 160 MiB)
    float*    dots = ws;                               // 33,554,432 fu (bf16 P packed in place)
    ushort_t* vb   = (ushort_t*)(ws + 33554432);       // 2,097,152 bf16
    ushort_t* vT   = (ushort_t*)(ws + 34603008);       // 2,097,152 bf16
    ushort_t* qb   = (ushort_t*)(ws + 35651584);       // 2,097,152 bf16
    ushort_t* kbuf = (ushort_t*)(ws + 36700160);       // 2,097,152 bf16
    ushort_t* xb   = (ushort_t*)(ws + 37748736);       // 2,097,152 bf16
    ushort_t* Wt   = (ushort_t*)(ws + 38797312);       // 3,145,728 bf16
    ushort_t* Wot  = (ushort_t*)(ws + 40370176);       // 1,048,576 bf16
    ushort_t* aob  = (ushort_t*)(ws + 40894464);       // 2,097,152 bf16

    k0_cvt<<<1024, 256, 0, stream>>>(x, xb, 262144);
    k0_tr<<<dim3(32, 32), 256, 0, stream>>>(Wq, Wt, 1024);
    k0_tr<<<dim3(64, 32), 256, 0, stream>>>(Wkv, Wt + 1024*1024, 2048);
    k0_tr<<<dim3(32, 32), 256, 0, stream>>>(Wout, Wot, 1024);
    k1_mfma<<<dim3(24, 16), 256, 0, stream>>>(xb, Wt, qb, kbuf, vb);
    k4_vt<<<dim3(2, 32, 32), 256, 0, stream>>>(vb, vT);
    k2_scores<<<dim3(1040), 256, 0, stream>>>(qb, kbuf, rel, pre, dots);
    k3_topk<<<dim3(2048), 1024, 0, stream>>>(dots, post);
    k5_pv<<<dim3(16, 32), 256, 0, stream>>>((const ushort_t*)dots, vT, aob);
    k6_mfma<<<dim3(8, 16), 256, 0, stream>>>(aob, Wot, bout, out);
}